// Round 8
// baseline (232.774 us; speedup 1.0000x reference)
//
#include <hip/hip_runtime.h>

// Problem: B=2, L=2048, E=1024, H=16, D=64
// softmax over QUERY axis (columns of the [L,M] score matrix per head).
//
// Softmax algebra: P[l,m] = 2^(S'[l,m] - d2_m), S' = log2(e)*S (folded into Q),
// d2_m = log2(sum_l 2^(S'[l,m])).  No max-subtraction: S ~ N(0,64) so
// |S'| < ~80 << 127 (f32 exp2 range); sum <= 2048*2^80 < f32 max.
//
// k_stats / k_attn: fragments read DIRECTLY from global (K+V = 512KB/head,
// L2-resident), ping-pong register prefetch (round-5/6 lesson), m-split /
// l-split 4 ways across waves, partials combined exactly at kernel end.
// k_proj_gemm: m97-structure global_load_lds staging (round-7, confirmed).
// Round-8: k_attn LDS 52KB limited residency to 3 blocks/CU (grid needs 4;
// occupancy 20%, all pipes <21%).  Ps double-buffer was useless (wave-private
// LDS is in-order within a wave) -> single buffer, and obuf ALIASES Ps
// (used only after the loop; barrier separates).  LDS 53248 -> 20480 B.

typedef _Float16 f16x8 __attribute__((ext_vector_type(8)));
typedef _Float16 f16x4 __attribute__((ext_vector_type(4)));
typedef __fp16 fp16x2 __attribute__((ext_vector_type(2)));  // cvt_pkrtz ret type
typedef float f32x4 __attribute__((ext_vector_type(4)));

#define MFMA(a, b, c) __builtin_amdgcn_mfma_f32_16x16x32_f16((a), (b), (c), 0, 0, 0)
#define EXP2(x) __builtin_amdgcn_exp2f(x)
#define LOG2E 1.44269504088896340736f

// global -> LDS direct DMA, 16B per lane; dest = lds base + lane*16 (linear!)
#define GLOAD_LDS(gp, lp)                                                    \
    __builtin_amdgcn_global_load_lds(                                        \
        (const __attribute__((address_space(1))) void*)(const void*)(gp),    \
        (__attribute__((address_space(3))) void*)(void*)(lp), 16, 0, 0)

// ---------------------------------------------------------------------------
// Kernel 1: fp32 -> f16 convert of x  (4096x1024)
// ---------------------------------------------------------------------------
__global__ __launch_bounds__(256) void k_convert_x(const float* __restrict__ x,
                                                   _Float16* __restrict__ xb) {
    int i = (blockIdx.x * 256 + threadIdx.x) * 4;
    float4 f = *(const float4*)(x + i);
    f16x4 o = {(_Float16)f.x, (_Float16)f.y, (_Float16)f.z, (_Float16)f.w};
    *(f16x4*)(xb + i) = o;
}

// ---------------------------------------------------------------------------
// Kernel 2: W (k-major [E][E]) -> W^T f16 ([3*E rows = n][E cols = k])
// ---------------------------------------------------------------------------
__global__ __launch_bounds__(256) void k_convert_wt(const float* __restrict__ Wq,
                                                    const float* __restrict__ Wk,
                                                    const float* __restrict__ Wv,
                                                    _Float16* __restrict__ wbt) {
    const int jz = blockIdx.z;
    const float* W = (jz == 0) ? Wq : (jz == 1) ? Wk : Wv;
    __shared__ float tile[64][65];
    const int k0 = blockIdx.y * 64, n0 = blockIdx.x * 64;
    for (int e = threadIdx.x; e < 4096; e += 256) {
        int r = e >> 6, c = e & 63;
        tile[r][c] = W[(k0 + r) * 1024 + n0 + c];
    }
    __syncthreads();
    for (int e = threadIdx.x; e < 4096; e += 256) {
        int r = e >> 6, c = e & 63;
        wbt[((size_t)jz * 1024 + n0 + r) * 1024 + k0 + c] = (_Float16)tile[c][r];
    }
}

// ---------------------------------------------------------------------------
// Kernel 3: fused QKV projection GEMM (Q scaled by log2e for exp2 downstream).
// m97 structure: 128x128 tile, BK=32, 4 waves (2x2), global_load_lds staging
// into linear [128][32] LDS, 16 MFMA + 8 ds_read_b128 per K-step.
// ---------------------------------------------------------------------------
__global__ __launch_bounds__(256) void k_proj_gemm(const _Float16* __restrict__ xb,
                                                   const _Float16* __restrict__ wbt,
                                                   const float* __restrict__ bq,
                                                   const float* __restrict__ bk,
                                                   const float* __restrict__ bv,
                                                   _Float16* __restrict__ Qb,
                                                   _Float16* __restrict__ Kb,
                                                   _Float16* __restrict__ Vt) {
    const int n0 = blockIdx.x * 128;
    const int m0 = blockIdx.y * 128;
    __shared__ _Float16 As[128][32];  // LINEAR (no pad): global_load_lds dest
    __shared__ _Float16 Bs[128][32];
    const int tid = threadIdx.x;
    const int lane = tid & 63, wv = tid >> 6;
    const int l15 = lane & 15, quad = lane >> 4;
    const int wr = wv >> 1, wc = wv & 1;
    // staging map: wave covers 16 rows/issue; lane i -> row grp*16 + (i>>2),
    // col (i&3)*8 f16 = LDS offset i*16B from &As[grp*16][0]  (linear match)
    const int srow = lane >> 2, scol = (lane & 3) * 8;

    f32x4 acc[4][4] = {};
    for (int k0 = 0; k0 < 1024; k0 += 32) {
        __syncthreads();  // previous tile fully consumed
        #pragma unroll
        for (int j = 0; j < 2; ++j) {
            const int grp = j * 4 + wv;  // 0..7: 8 groups of 16 rows
            GLOAD_LDS(&xb[(size_t)(m0 + grp * 16 + srow) * 1024 + k0 + scol],
                      &As[grp * 16][0]);
            GLOAD_LDS(&wbt[(size_t)(n0 + grp * 16 + srow) * 1024 + k0 + scol],
                      &Bs[grp * 16][0]);
        }
        __syncthreads();  // compiler drains vmcnt before barrier
        f16x8 af[4], bf[4];
        #pragma unroll
        for (int i = 0; i < 4; ++i) {
            af[i] = *(const f16x8*)&As[wr * 64 + i * 16 + l15][quad * 8];
            bf[i] = *(const f16x8*)&Bs[wc * 64 + i * 16 + l15][quad * 8];
        }
        #pragma unroll
        for (int i = 0; i < 4; ++i)
            #pragma unroll
            for (int j = 0; j < 4; ++j)
                acc[i][j] = MFMA(af[i], bf[j], acc[i][j]);
    }

    const int proj = n0 >> 10;
    const float* bias = (proj == 0) ? bq : (proj == 1) ? bk : bv;
    const float scale = (proj == 0) ? LOG2E : 1.0f;
    for (int j = 0; j < 4; ++j) {
        int n = n0 + wc * 64 + j * 16 + l15;
        int nn = n & 1023;
        float bsv = bias[nn];
        int h = nn >> 6, d = nn & 63;
        for (int i = 0; i < 4; ++i) {
            for (int r = 0; r < 4; ++r) {
                int t = m0 + wr * 64 + i * 16 + quad * 4 + r;
                int b = t >> 11, l = t & 2047;
                _Float16 val = (_Float16)((acc[i][j][r] + bsv) * scale);
                int bh = b * 16 + h;
                if (proj == 0)
                    Qb[((size_t)bh * 2048 + l) * 64 + d] = val;
                else if (proj == 1)
                    Kb[((size_t)bh * 2048 + l) * 64 + d] = val;
                else
                    Vt[((size_t)bh * 64 + d) * 2048 + l] = val;
            }
        }
    }
}

// ---------------------------------------------------------------------------
// Kernel 4: column stats d2_m = log2(sum_l 2^(S'[l,m])).
// Block = 64 m-cols of one head; 4 waves each own an l-quarter (512 l).
// K frags loop-invariant in regs; Q ping-pong-prefetched (chunk of 32 l).
// Partial exp-sums combined exactly in LDS at the end.  1024 blocks.
// ---------------------------------------------------------------------------
__global__ __launch_bounds__(256, 2) void k_stats(const _Float16* __restrict__ Qb,
                                                  const _Float16* __restrict__ Kb,
                                                  float* __restrict__ d2) {
    __shared__ float sred[4][4][64];            // [wave][s][lane] partials, 4KB
    const int id = blockIdx.x;                  // 1024 blocks
    const int wk = (id & 7) * 128 + (id >> 3);  // XCD swizzle: same-head -> same XCD
    const int bh = wk >> 5;                     // 32 heads
    const int mt = wk & 31;                     // 32 m-tiles of 64
    const int lane = threadIdx.x & 63, wv = threadIdx.x >> 6;
    const int l15 = lane & 15, quad = lane >> 4;
    const int m0 = mt * 64;
    const int lbase = wv * 512;                 // wave's l-quarter
    const size_t base = (size_t)bh * 2048 * 64;
    const _Float16* Kp = Kb + base;
    const _Float16* qb = Qb + base + (size_t)(lbase + l15) * 64 + quad * 8;

    // K fragments (X-operand rows = m): loop-invariant
    f16x8 bf[4][2];
    #pragma unroll
    for (int s = 0; s < 4; ++s) {
        bf[s][0] = *(const f16x8*)&Kp[(size_t)(m0 + s * 16 + l15) * 64 + quad * 8];
        bf[s][1] = *(const f16x8*)&Kp[(size_t)(m0 + s * 16 + l15) * 64 + 32 + quad * 8];
    }
    float rs[4] = {0.f, 0.f, 0.f, 0.f};
    f16x8 qd[2][2][2];  // [pingpong][lt][half] -- all indices compile-time

#define SLOAD(P, LC) do {                                          \
        qd[P][0][0] = *(const f16x8*)&qb[(LC)*64];                 \
        qd[P][0][1] = *(const f16x8*)&qb[(LC)*64 + 32];            \
        qd[P][1][0] = *(const f16x8*)&qb[(LC)*64 + 1024];          \
        qd[P][1][1] = *(const f16x8*)&qb[(LC)*64 + 1056];          \
    } while (0)

#define SCOMP(P) do {                                              \
        __builtin_amdgcn_s_setprio(1);                             \
        _Pragma("unroll")                                          \
        for (int s = 0; s < 4; ++s) {                              \
            _Pragma("unroll")                                      \
            for (int lt = 0; lt < 2; ++lt) {                       \
                f32x4 a = {};                                      \
                a = MFMA(qd[P][lt][0], bf[s][0], a);               \
                a = MFMA(qd[P][lt][1], bf[s][1], a);               \
                rs[s] += EXP2(a[0]) + EXP2(a[1]) +                 \
                         EXP2(a[2]) + EXP2(a[3]);                  \
            }                                                      \
        }                                                          \
        __builtin_amdgcn_s_setprio(0);                             \
    } while (0)

    SLOAD(0, 0);
    #pragma unroll
    for (int it = 0; it < 8; ++it) {
        const int cA = it * 64;
        const int cB = cA + 32;
        const int cN = (it < 7) ? cA + 64 : 0;  // last: dead in-bounds reload
        SLOAD(1, cB);
        SCOMP(0);
        SLOAD(0, cN);
        SCOMP(1);
    }
#undef SLOAD
#undef SCOMP

    // combine wave partials (exact: plain sum)
    #pragma unroll
    for (int s = 0; s < 4; ++s) sred[wv][s][lane] = rs[s];
    __syncthreads();
    if (wv == 0) {
        #pragma unroll
        for (int s = 0; s < 4; ++s) {
            float t = sred[0][s][lane] + sred[1][s][lane] + sred[2][s][lane] + sred[3][s][lane];
            t += __shfl_xor(t, 16, 64);
            t += __shfl_xor(t, 32, 64);
            rs[s] = t;
        }
        float myz = (quad == 0) ? rs[0] : (quad == 1) ? rs[1] : (quad == 2) ? rs[2] : rs[3];
        d2[bh * 2048 + m0 + quad * 16 + l15] = __builtin_amdgcn_logf(myz);  // v_log = log2
    }
}

// ---------------------------------------------------------------------------
// Kernel 5: output. Block = 64 l-rows of one head; 4 waves each own an
// m-quarter (512 m).  K/V/d2 ping-pong-prefetched a full 32-m chunk ahead.
// Swapped QK -> packed P -> ds_write_b64 (SINGLE-buffer Ps: wave-private LDS
// is in-order within a wave); swapped PV -> float4 epilogue.  obuf for the
// final partial-combine ALIASES Ps (barrier-separated).  LDS = 20,480 B ->
// full grid co-resident (4 blocks/CU, 16 waves/CU).  1024 blocks.
// ---------------------------------------------------------------------------
__global__ __launch_bounds__(256, 2) void k_attn(const _Float16* __restrict__ Qb,
                                                 const _Float16* __restrict__ Kb,
                                                 const _Float16* __restrict__ Vt,
                                                 const float* __restrict__ d2,
                                                 float* __restrict__ out) {
    __shared__ __align__(16) char smem[20480];  // Ps [4][64][40] f16 (20KB)
    _Float16 (*Ps)[64][40] = (_Float16(*)[64][40])smem;      // during main loop
    f32x4 (*obuf)[4][64] = (f32x4(*)[4][64])smem;            // after (aliased)
    const int id = blockIdx.x;                  // 1024 blocks
    const int wk = (id & 7) * 128 + (id >> 3);  // XCD swizzle
    const int bh = wk >> 5;                     // 32 heads
    const int ltile = wk & 31;                  // 32 l-tiles of 64
    const int b = bh >> 4, h = bh & 15;
    const int lane = threadIdx.x & 63, wv = threadIdx.x >> 6;
    const int l15 = lane & 15, quad = lane >> 4;
    const int l0 = ltile * 64;                  // block's 64 l-rows
    const int mbase = wv * 512;                 // wave's m-quarter
    const size_t base = (size_t)bh * 2048 * 64;
    const _Float16* Qp = Qb + base;
    // per-lane fragment base pointers (all loads = base + compile-time offset)
    const _Float16* kb = Kb + base + (size_t)(mbase + l15) * 64 + quad * 8;
    const _Float16* vb = Vt + base + (size_t)l15 * 2048 + mbase + quad * 8;
    const float* db = d2 + bh * 2048 + mbase + quad * 4;

    // Q fragments (Y-operand rows = l): loop-invariant
    f16x8 qf[4][2];
    #pragma unroll
    for (int lt = 0; lt < 4; ++lt) {
        qf[lt][0] = *(const f16x8*)&Qp[(size_t)(l0 + lt * 16 + l15) * 64 + quad * 8];
        qf[lt][1] = *(const f16x8*)&Qp[(size_t)(l0 + lt * 16 + l15) * 64 + 32 + quad * 8];
    }
    f32x4 oacc[4][4] = {};  // [dt][lt]: lane holds out[d=dt*16+quad*4+r][l=lt*16+l15]
    f16x8 kf[2][2][2];      // [pingpong][s][half]
    f16x8 vf[2][4];         // [pingpong][dt]
    f32x4 dv[2][2];         // [pingpong][s]

#define ALOAD(P, MC) do {                                          \
        kf[P][0][0] = *(const f16x8*)&kb[(MC)*64];                 \
        kf[P][0][1] = *(const f16x8*)&kb[(MC)*64 + 32];            \
        kf[P][1][0] = *(const f16x8*)&kb[(MC)*64 + 1024];          \
        kf[P][1][1] = *(const f16x8*)&kb[(MC)*64 + 1056];          \
        dv[P][0] = *(const f32x4*)&db[(MC)];                       \
        dv[P][1] = *(const f32x4*)&db[(MC) + 16];                  \
        vf[P][0] = *(const f16x8*)&vb[(MC)];                       \
        vf[P][1] = *(const f16x8*)&vb[(MC) + 32768];               \
        vf[P][2] = *(const f16x8*)&vb[(MC) + 65536];               \
        vf[P][3] = *(const f16x8*)&vb[(MC) + 98304];               \
    } while (0)

#define ACOMP(P) do {                                                         \
        __builtin_amdgcn_s_setprio(1);                                        \
        _Pragma("unroll")                                                     \
        for (int s = 0; s < 2; ++s) {                                         \
            _Pragma("unroll")                                                 \
            for (int lt = 0; lt < 4; ++lt) {                                  \
                f32x4 a = {};                                                 \
                a = MFMA(kf[P][s][0], qf[lt][0], a);                          \
                a = MFMA(kf[P][s][1], qf[lt][1], a);                          \
                union { fp16x2 hh[2]; f16x4 v; } u;                           \
                u.hh[0] = __builtin_amdgcn_cvt_pkrtz(EXP2(a[0] - dv[P][s][0]),\
                                                     EXP2(a[1] - dv[P][s][1]));\
                u.hh[1] = __builtin_amdgcn_cvt_pkrtz(EXP2(a[2] - dv[P][s][2]),\
                                                     EXP2(a[3] - dv[P][s][3]));\
                *(f16x4*)&Ps[wv][lt * 16 + l15][s * 16 + quad * 4] = u.v;     \
            }                                                                 \
        }                                                                     \
        _Pragma("unroll")                                                     \
        for (int lt = 0; lt < 4; ++lt) {                                      \
            f16x8 pf = *(const f16x8*)&Ps[wv][lt * 16 + l15][quad * 8];       \
            _Pragma("unroll")                                                 \
            for (int dt = 0; dt < 4; ++dt)                                    \
                oacc[dt][lt] = MFMA(vf[P][dt], pf, oacc[dt][lt]);             \
        }                                                                     \
        __builtin_amdgcn_s_setprio(0);                                        \
    } while (0)

    ALOAD(0, 0);
    #pragma unroll
    for (int it = 0; it < 8; ++it) {
        const int cA = it * 64;
        const int cB = cA + 32;
        const int cN = (it < 7) ? cA + 64 : 0;  // last: dead in-bounds reload
        ALOAD(1, cB);   // prefetch chunk B (covered by compute of A)
        ACOMP(0);
        ALOAD(0, cN);   // prefetch next A (covered by compute of B)
        ACOMP(1);
    }
#undef ALOAD
#undef ACOMP

    __syncthreads();  // all Ps reads done before obuf (aliased) is written
    // combine the 4 m-quarter partials (exact) one dt-slab at a time, then
    // wave 0 writes float4-coalesced output.
    #pragma unroll
    for (int dt = 0; dt < 4; ++dt) {
        if (wv > 0) {
            #pragma unroll
            for (int lt = 0; lt < 4; ++lt) obuf[wv - 1][lt][lane] = oacc[dt][lt];
        }
        __syncthreads();
        if (wv == 0) {
            #pragma unroll
            for (int lt = 0; lt < 4; ++lt) {
                f32x4 o = oacc[dt][lt] + obuf[0][lt][lane] + obuf[1][lt][lane] + obuf[2][lt][lane];
                int l = l0 + lt * 16 + l15;
                float4 o4 = {o[0], o[1], o[2], o[3]};
                *(float4*)&out[((size_t)(b * 2048 + l)) * 1024 + h * 64 + dt * 16 + quad * 4] = o4;
            }
        }
        __syncthreads();
    }
}

// ---------------------------------------------------------------------------
// Workspace layout (bytes):
//  0        xb   : 4096*1024 f16          = 8 MB
//  8 MB     wbt  : 3072*1024 f16          = 6 MB
// 14 MB     Qb   : 32*2048*64 f16         = 8 MB   (pre-scaled by log2e)
// 22 MB     Kb   : 32*2048*64 f16         = 8 MB
// 30 MB     Vt   : 32*64*2048 f16         = 8 MB
// 38 MB     d2   : 32*2048 f32            = 256 KB (log2 of column expsum)
// ---------------------------------------------------------------------------
extern "C" void kernel_launch(void* const* d_in, const int* in_sizes, int n_in,
                              void* d_out, int out_size, void* d_ws, size_t ws_size,
                              hipStream_t stream) {
    const float* x  = (const float*)d_in[0];
    const float* Wq = (const float*)d_in[1];
    const float* bq = (const float*)d_in[2];
    const float* Wk = (const float*)d_in[3];
    const float* bk = (const float*)d_in[4];
    const float* Wv = (const float*)d_in[5];
    const float* bv = (const float*)d_in[6];
    float* out = (float*)d_out;

    char* w = (char*)d_ws;
    _Float16* xb  = (_Float16*)(w);
    _Float16* wbt = (_Float16*)(w + (size_t)(8 << 20));
    _Float16* Qb  = (_Float16*)(w + (size_t)(14 << 20));
    _Float16* Kb  = (_Float16*)(w + (size_t)(22 << 20));
    _Float16* Vt  = (_Float16*)(w + (size_t)(30 << 20));
    float* d2     = (float*)(w + (size_t)(38 << 20));

    k_convert_x<<<4096, 256, 0, stream>>>(x, xb);
    k_convert_wt<<<dim3(16, 16, 3), 256, 0, stream>>>(Wq, Wk, Wv, wbt);
    k_proj_gemm<<<dim3(24, 32), 256, 0, stream>>>(xb, wbt, bq, bk, bv, Qb, Kb, Vt);
    k_stats<<<1024, 256, 0, stream>>>(Qb, Kb, d2);
    k_attn<<<1024, 256, 0, stream>>>(Qb, Kb, Vt, d2, out);
}

// Round 10
// 230.428 us; speedup vs baseline: 1.0102x; 1.0102x over previous
//
#include <hip/hip_runtime.h>

// Problem: B=2, L=2048, E=1024, H=16, D=64
// softmax over QUERY axis (columns of the [L,M] score matrix per head).
//
// Softmax algebra: P[l,m] = 2^(S'[l,m] - d2_m), S' = log2(e)*S (folded into Q),
// d2_m = log2(sum_l 2^(S'[l,m])).  No max-subtraction: S ~ N(0,64) so
// |S'| < ~80 << 127 (f32 exp2 range); sum <= 2048*2^80 < f32 max.
//
// k_stats / k_attn: fragments read DIRECTLY from global (K+V = 512KB/head,
// L2-resident), ping-pong register prefetch, m-split / l-split 4 ways across
// waves, partials combined exactly at kernel end.  1024 blocks each.
// k_proj_gemm: m97-structure global_load_lds staging (round-7, confirmed).
// Round-9 lesson: ds_bpermute is a PULL -- subtile select must happen at the
// DESTINATION (dest q needs s=q>>1; its sources are quads {0,2}/{1,3} for any
// q).  Two dests (q, q+2) pull DIFFERENT s from the SAME source lane, so each
// output word needs TWO bpermutes (sources offer c[0] and c[1]) + dest-side
// cndmask on the dest's own quad.  Mapping cross-checked against the verified
// round-8 LDS path (Ps[l][m] write / pf read agree).

typedef _Float16 f16x8 __attribute__((ext_vector_type(8)));
typedef _Float16 f16x4 __attribute__((ext_vector_type(4)));
typedef __fp16 fp16x2 __attribute__((ext_vector_type(2)));  // cvt_pkrtz ret type
typedef float f32x4 __attribute__((ext_vector_type(4)));

#define MFMA(a, b, c) __builtin_amdgcn_mfma_f32_16x16x32_f16((a), (b), (c), 0, 0, 0)
#define EXP2(x) __builtin_amdgcn_exp2f(x)
#define LOG2E 1.44269504088896340736f

// global -> LDS direct DMA, 16B per lane; dest = lds base + lane*16 (linear!)
#define GLOAD_LDS(gp, lp)                                                    \
    __builtin_amdgcn_global_load_lds(                                        \
        (const __attribute__((address_space(1))) void*)(const void*)(gp),    \
        (__attribute__((address_space(3))) void*)(void*)(lp), 16, 0, 0)

// ---------------------------------------------------------------------------
// Kernel 1: fp32 -> f16 convert of x  (4096x1024)
// ---------------------------------------------------------------------------
__global__ __launch_bounds__(256) void k_convert_x(const float* __restrict__ x,
                                                   _Float16* __restrict__ xb) {
    int i = (blockIdx.x * 256 + threadIdx.x) * 4;
    float4 f = *(const float4*)(x + i);
    f16x4 o = {(_Float16)f.x, (_Float16)f.y, (_Float16)f.z, (_Float16)f.w};
    *(f16x4*)(xb + i) = o;
}

// ---------------------------------------------------------------------------
// Kernel 2: W (k-major [E][E]) -> W^T f16 ([3*E rows = n][E cols = k])
// ---------------------------------------------------------------------------
__global__ __launch_bounds__(256) void k_convert_wt(const float* __restrict__ Wq,
                                                    const float* __restrict__ Wk,
                                                    const float* __restrict__ Wv,
                                                    _Float16* __restrict__ wbt) {
    const int jz = blockIdx.z;
    const float* W = (jz == 0) ? Wq : (jz == 1) ? Wk : Wv;
    __shared__ float tile[64][65];
    const int k0 = blockIdx.y * 64, n0 = blockIdx.x * 64;
    for (int e = threadIdx.x; e < 4096; e += 256) {
        int r = e >> 6, c = e & 63;
        tile[r][c] = W[(k0 + r) * 1024 + n0 + c];
    }
    __syncthreads();
    for (int e = threadIdx.x; e < 4096; e += 256) {
        int r = e >> 6, c = e & 63;
        wbt[((size_t)jz * 1024 + n0 + r) * 1024 + k0 + c] = (_Float16)tile[c][r];
    }
}

// ---------------------------------------------------------------------------
// Kernel 3: fused QKV projection GEMM (Q scaled by log2e for exp2 downstream).
// m97 structure: 128x128 tile, BK=32, 4 waves (2x2), global_load_lds staging
// into linear [128][32] LDS, 16 MFMA + 8 ds_read_b128 per K-step.
// ---------------------------------------------------------------------------
__global__ __launch_bounds__(256) void k_proj_gemm(const _Float16* __restrict__ xb,
                                                   const _Float16* __restrict__ wbt,
                                                   const float* __restrict__ bq,
                                                   const float* __restrict__ bk,
                                                   const float* __restrict__ bv,
                                                   _Float16* __restrict__ Qb,
                                                   _Float16* __restrict__ Kb,
                                                   _Float16* __restrict__ Vt) {
    const int n0 = blockIdx.x * 128;
    const int m0 = blockIdx.y * 128;
    __shared__ _Float16 As[128][32];  // LINEAR (no pad): global_load_lds dest
    __shared__ _Float16 Bs[128][32];
    const int tid = threadIdx.x;
    const int lane = tid & 63, wv = tid >> 6;
    const int l15 = lane & 15, quad = lane >> 4;
    const int wr = wv >> 1, wc = wv & 1;
    // staging map: wave covers 16 rows/issue; lane i -> row grp*16 + (i>>2),
    // col (i&3)*8 f16 = LDS offset i*16B from &As[grp*16][0]  (linear match)
    const int srow = lane >> 2, scol = (lane & 3) * 8;

    f32x4 acc[4][4] = {};
    for (int k0 = 0; k0 < 1024; k0 += 32) {
        __syncthreads();  // previous tile fully consumed
        #pragma unroll
        for (int j = 0; j < 2; ++j) {
            const int grp = j * 4 + wv;  // 0..7: 8 groups of 16 rows
            GLOAD_LDS(&xb[(size_t)(m0 + grp * 16 + srow) * 1024 + k0 + scol],
                      &As[grp * 16][0]);
            GLOAD_LDS(&wbt[(size_t)(n0 + grp * 16 + srow) * 1024 + k0 + scol],
                      &Bs[grp * 16][0]);
        }
        __syncthreads();  // compiler drains vmcnt before barrier
        f16x8 af[4], bf[4];
        #pragma unroll
        for (int i = 0; i < 4; ++i) {
            af[i] = *(const f16x8*)&As[wr * 64 + i * 16 + l15][quad * 8];
            bf[i] = *(const f16x8*)&Bs[wc * 64 + i * 16 + l15][quad * 8];
        }
        #pragma unroll
        for (int i = 0; i < 4; ++i)
            #pragma unroll
            for (int j = 0; j < 4; ++j)
                acc[i][j] = MFMA(af[i], bf[j], acc[i][j]);
    }

    const int proj = n0 >> 10;
    const float* bias = (proj == 0) ? bq : (proj == 1) ? bk : bv;
    const float scale = (proj == 0) ? LOG2E : 1.0f;
    for (int j = 0; j < 4; ++j) {
        int n = n0 + wc * 64 + j * 16 + l15;
        int nn = n & 1023;
        float bsv = bias[nn];
        int h = nn >> 6, d = nn & 63;
        for (int i = 0; i < 4; ++i) {
            for (int r = 0; r < 4; ++r) {
                int t = m0 + wr * 64 + i * 16 + quad * 4 + r;
                int b = t >> 11, l = t & 2047;
                _Float16 val = (_Float16)((acc[i][j][r] + bsv) * scale);
                int bh = b * 16 + h;
                if (proj == 0)
                    Qb[((size_t)bh * 2048 + l) * 64 + d] = val;
                else if (proj == 1)
                    Kb[((size_t)bh * 2048 + l) * 64 + d] = val;
                else
                    Vt[((size_t)bh * 64 + d) * 2048 + l] = val;
            }
        }
    }
}

// ---------------------------------------------------------------------------
// Kernel 4: column stats d2_m = log2(sum_l 2^(S'[l,m])).
// Block = 64 m-cols of one head; 4 waves each own an l-quarter (512 l).
// K frags loop-invariant in regs; Q ping-pong-prefetched (chunk of 32 l).
// Partial exp-sums combined exactly in LDS at the end.  1024 blocks.
// ---------------------------------------------------------------------------
__global__ __launch_bounds__(256, 2) void k_stats(const _Float16* __restrict__ Qb,
                                                  const _Float16* __restrict__ Kb,
                                                  float* __restrict__ d2) {
    __shared__ float sred[4][4][64];            // [wave][s][lane] partials, 4KB
    const int id = blockIdx.x;                  // 1024 blocks
    const int wk = (id & 7) * 128 + (id >> 3);  // XCD swizzle: same-head -> same XCD
    const int bh = wk >> 5;                     // 32 heads
    const int mt = wk & 31;                     // 32 m-tiles of 64
    const int lane = threadIdx.x & 63, wv = threadIdx.x >> 6;
    const int l15 = lane & 15, quad = lane >> 4;
    const int m0 = mt * 64;
    const int lbase = wv * 512;                 // wave's l-quarter
    const size_t base = (size_t)bh * 2048 * 64;
    const _Float16* Kp = Kb + base;
    const _Float16* qb = Qb + base + (size_t)(lbase + l15) * 64 + quad * 8;

    // K fragments (X-operand rows = m): loop-invariant
    f16x8 bf[4][2];
    #pragma unroll
    for (int s = 0; s < 4; ++s) {
        bf[s][0] = *(const f16x8*)&Kp[(size_t)(m0 + s * 16 + l15) * 64 + quad * 8];
        bf[s][1] = *(const f16x8*)&Kp[(size_t)(m0 + s * 16 + l15) * 64 + 32 + quad * 8];
    }
    float rs[4] = {0.f, 0.f, 0.f, 0.f};
    f16x8 qd[2][2][2];  // [pingpong][lt][half] -- all indices compile-time

#define SLOAD(P, LC) do {                                          \
        qd[P][0][0] = *(const f16x8*)&qb[(LC)*64];                 \
        qd[P][0][1] = *(const f16x8*)&qb[(LC)*64 + 32];            \
        qd[P][1][0] = *(const f16x8*)&qb[(LC)*64 + 1024];          \
        qd[P][1][1] = *(const f16x8*)&qb[(LC)*64 + 1056];          \
    } while (0)

#define SCOMP(P) do {                                              \
        __builtin_amdgcn_s_setprio(1);                             \
        _Pragma("unroll")                                          \
        for (int s = 0; s < 4; ++s) {                              \
            _Pragma("unroll")                                      \
            for (int lt = 0; lt < 2; ++lt) {                       \
                f32x4 a = {};                                      \
                a = MFMA(qd[P][lt][0], bf[s][0], a);               \
                a = MFMA(qd[P][lt][1], bf[s][1], a);               \
                rs[s] += EXP2(a[0]) + EXP2(a[1]) +                 \
                         EXP2(a[2]) + EXP2(a[3]);                  \
            }                                                      \
        }                                                          \
        __builtin_amdgcn_s_setprio(0);                             \
    } while (0)

    SLOAD(0, 0);
    #pragma unroll
    for (int it = 0; it < 8; ++it) {
        const int cA = it * 64;
        const int cB = cA + 32;
        const int cN = (it < 7) ? cA + 64 : 0;  // last: dead in-bounds reload
        SLOAD(1, cB);
        SCOMP(0);
        SLOAD(0, cN);
        SCOMP(1);
    }
#undef SLOAD
#undef SCOMP

    // combine wave partials (exact: plain sum)
    #pragma unroll
    for (int s = 0; s < 4; ++s) sred[wv][s][lane] = rs[s];
    __syncthreads();
    if (wv == 0) {
        #pragma unroll
        for (int s = 0; s < 4; ++s) {
            float t = sred[0][s][lane] + sred[1][s][lane] + sred[2][s][lane] + sred[3][s][lane];
            t += __shfl_xor(t, 16, 64);
            t += __shfl_xor(t, 32, 64);
            rs[s] = t;
        }
        float myz = (quad == 0) ? rs[0] : (quad == 1) ? rs[1] : (quad == 2) ? rs[2] : rs[3];
        d2[bh * 2048 + m0 + quad * 16 + l15] = __builtin_amdgcn_logf(myz);  // v_log = log2
    }
}

// ---------------------------------------------------------------------------
// Kernel 5: output. Block = 64 l-rows of one head; 4 waves each own an
// m-quarter (512 m).  K/V/d2 ping-pong-prefetched a full 32-m chunk ahead.
// Swapped QK -> P redistributed IN-REGISTER to the PV B-fragment layout:
// per word slot, TWO ds_bpermutes (sources offer the s=0 and s=1 pair) +
// dest-side v_cndmask on the DEST's quad (round-9 fix: bpermute is a pull;
// source-side subtile select was wrong).  Swapped PV -> float4 epilogue.
// Partial O summed exactly at the end.  LDS = 12KB obuf only.  1024 blocks.
//
// Mapping (verified against the round-8 LDS path): source lane (l=l15,q')
// holds pairs c[s][0]=P[m=s*16+q'*4+{0,1}][l], c[s][1]=...{2,3}.  Dest lane
// (l,q) B-fragment word w0=P[m=8q+{0,1}][l] etc: s=q>>1, words {w0,w1} from
// source lane (l, 2(q&1)) [= srcA: quads 0/2], {w2,w3} from (l, 2(q&1)+1)
// [= srcB: quads 1/3].
// ---------------------------------------------------------------------------
__global__ __launch_bounds__(256, 2) void k_attn(const _Float16* __restrict__ Qb,
                                                 const _Float16* __restrict__ Kb,
                                                 const _Float16* __restrict__ Vt,
                                                 const float* __restrict__ d2,
                                                 float* __restrict__ out) {
    __shared__ f32x4 obuf[3][4][64];            // [wave-1][lt][lane] combine, 12 KB
    const int id = blockIdx.x;                  // 1024 blocks
    const int wk = (id & 7) * 128 + (id >> 3);  // XCD swizzle
    const int bh = wk >> 5;                     // 32 heads
    const int ltile = wk & 31;                  // 32 l-tiles of 64
    const int b = bh >> 4, h = bh & 15;
    const int lane = threadIdx.x & 63, wv = threadIdx.x >> 6;
    const int l15 = lane & 15, quad = lane >> 4;
    const int l0 = ltile * 64;                  // block's 64 l-rows
    const int mbase = wv * 512;                 // wave's m-quarter
    const size_t base = (size_t)bh * 2048 * 64;
    const _Float16* Qp = Qb + base;
    // per-lane fragment base pointers (all loads = base + compile-time offset)
    const _Float16* kb = Kb + base + (size_t)(mbase + l15) * 64 + quad * 8;
    const _Float16* vb = Vt + base + (size_t)l15 * 2048 + mbase + quad * 8;
    const float* db = d2 + bh * 2048 + mbase + quad * 4;
    // bpermute byte-indices (pull): srcA = lane l15 + 32*(q&1) (quads 0/2),
    // srcB = srcA + 16 lanes (quads 1/3).  Index is lane*4 bytes.
    const int srcA = (l15 + ((quad & 1) << 5)) << 2;
    const int srcB = srcA + 64;
    const bool slo = (quad < 2);                // dest-side subtile select

    // Q fragments (Y-operand rows = l): loop-invariant
    f16x8 qf[4][2];
    #pragma unroll
    for (int lt = 0; lt < 4; ++lt) {
        qf[lt][0] = *(const f16x8*)&Qp[(size_t)(l0 + lt * 16 + l15) * 64 + quad * 8];
        qf[lt][1] = *(const f16x8*)&Qp[(size_t)(l0 + lt * 16 + l15) * 64 + 32 + quad * 8];
    }
    f32x4 oacc[4][4] = {};  // [dt][lt]: lane holds out[d=dt*16+quad*4+r][l=lt*16+l15]
    f16x8 kf[2][2][2];      // [pingpong][s][half]
    f16x8 vf[2][4];         // [pingpong][dt]
    f32x4 dv[2][2];         // [pingpong][s]

#define ALOAD(P, MC) do {                                          \
        kf[P][0][0] = *(const f16x8*)&kb[(MC)*64];                 \
        kf[P][0][1] = *(const f16x8*)&kb[(MC)*64 + 32];            \
        kf[P][1][0] = *(const f16x8*)&kb[(MC)*64 + 1024];          \
        kf[P][1][1] = *(const f16x8*)&kb[(MC)*64 + 1056];          \
        dv[P][0] = *(const f32x4*)&db[(MC)];                       \
        dv[P][1] = *(const f32x4*)&db[(MC) + 16];                  \
        vf[P][0] = *(const f16x8*)&vb[(MC)];                       \
        vf[P][1] = *(const f16x8*)&vb[(MC) + 32768];               \
        vf[P][2] = *(const f16x8*)&vb[(MC) + 65536];               \
        vf[P][3] = *(const f16x8*)&vb[(MC) + 98304];               \
    } while (0)

#define ACOMP(P) do {                                                         \
        __builtin_amdgcn_s_setprio(1);                                        \
        _Pragma("unroll")                                                     \
        for (int lt = 0; lt < 4; ++lt) {                                      \
            unsigned int c[2][2];                                             \
            _Pragma("unroll")                                                 \
            for (int s = 0; s < 2; ++s) {                                     \
                f32x4 a = {};                                                 \
                a = MFMA(kf[P][s][0], qf[lt][0], a);                          \
                a = MFMA(kf[P][s][1], qf[lt][1], a);                          \
                union { fp16x2 hh; unsigned int u; } u0, u1;                  \
                u0.hh = __builtin_amdgcn_cvt_pkrtz(EXP2(a[0] - dv[P][s][0]),  \
                                                   EXP2(a[1] - dv[P][s][1])); \
                u1.hh = __builtin_amdgcn_cvt_pkrtz(EXP2(a[2] - dv[P][s][2]),  \
                                                   EXP2(a[3] - dv[P][s][3])); \
                c[s][0] = u0.u;                                               \
                c[s][1] = u1.u;                                               \
            }                                                                 \
            int t0a = __builtin_amdgcn_ds_bpermute(srcA, (int)c[0][0]);       \
            int t1a = __builtin_amdgcn_ds_bpermute(srcA, (int)c[1][0]);       \
            int t0b = __builtin_amdgcn_ds_bpermute(srcA, (int)c[0][1]);       \
            int t1b = __builtin_amdgcn_ds_bpermute(srcA, (int)c[1][1]);       \
            int t0c = __builtin_amdgcn_ds_bpermute(srcB, (int)c[0][0]);       \
            int t1c = __builtin_amdgcn_ds_bpermute(srcB, (int)c[1][0]);       \
            int t0d = __builtin_amdgcn_ds_bpermute(srcB, (int)c[0][1]);       \
            int t1d = __builtin_amdgcn_ds_bpermute(srcB, (int)c[1][1]);       \
            union { int w[4]; f16x8 v; } pu;                                  \
            pu.w[0] = slo ? t0a : t1a;                                        \
            pu.w[1] = slo ? t0b : t1b;                                        \
            pu.w[2] = slo ? t0c : t1c;                                        \
            pu.w[3] = slo ? t0d : t1d;                                        \
            _Pragma("unroll")                                                 \
            for (int dt = 0; dt < 4; ++dt)                                    \
                oacc[dt][lt] = MFMA(vf[P][dt], pu.v, oacc[dt][lt]);           \
        }                                                                     \
        __builtin_amdgcn_s_setprio(0);                                        \
    } while (0)

    ALOAD(0, 0);
    #pragma unroll
    for (int it = 0; it < 8; ++it) {
        const int cA = it * 64;
        const int cB = cA + 32;
        const int cN = (it < 7) ? cA + 64 : 0;  // last: dead in-bounds reload
        ALOAD(1, cB);   // prefetch chunk B (covered by compute of A)
        ACOMP(0);
        ALOAD(0, cN);   // prefetch next A (covered by compute of B)
        ACOMP(1);
    }
#undef ALOAD
#undef ACOMP

    // combine the 4 m-quarter partials (exact) one dt-slab at a time, then
    // wave 0 writes float4-coalesced output.
    #pragma unroll
    for (int dt = 0; dt < 4; ++dt) {
        if (wv > 0) {
            #pragma unroll
            for (int lt = 0; lt < 4; ++lt) obuf[wv - 1][lt][lane] = oacc[dt][lt];
        }
        __syncthreads();
        if (wv == 0) {
            #pragma unroll
            for (int lt = 0; lt < 4; ++lt) {
                f32x4 o = oacc[dt][lt] + obuf[0][lt][lane] + obuf[1][lt][lane] + obuf[2][lt][lane];
                int l = l0 + lt * 16 + l15;
                float4 o4 = {o[0], o[1], o[2], o[3]};
                *(float4*)&out[((size_t)(b * 2048 + l)) * 1024 + h * 64 + dt * 16 + quad * 4] = o4;
            }
        }
        __syncthreads();
    }
}

// ---------------------------------------------------------------------------
// Workspace layout (bytes):
//  0        xb   : 4096*1024 f16          = 8 MB
//  8 MB     wbt  : 3072*1024 f16          = 6 MB
// 14 MB     Qb   : 32*2048*64 f16         = 8 MB   (pre-scaled by log2e)
// 22 MB     Kb   : 32*2048*64 f16         = 8 MB
// 30 MB     Vt   : 32*64*2048 f16         = 8 MB
// 38 MB     d2   : 32*2048 f32            = 256 KB (log2 of column expsum)
// ---------------------------------------------------------------------------
extern "C" void kernel_launch(void* const* d_in, const int* in_sizes, int n_in,
                              void* d_out, int out_size, void* d_ws, size_t ws_size,
                              hipStream_t stream) {
    const float* x  = (const float*)d_in[0];
    const float* Wq = (const float*)d_in[1];
    const float* bq = (const float*)d_in[2];
    const float* Wk = (const float*)d_in[3];
    const float* bk = (const float*)d_in[4];
    const float* Wv = (const float*)d_in[5];
    const float* bv = (const float*)d_in[6];
    float* out = (float*)d_out;

    char* w = (char*)d_ws;
    _Float16* xb  = (_Float16*)(w);
    _Float16* wbt = (_Float16*)(w + (size_t)(8 << 20));
    _Float16* Qb  = (_Float16*)(w + (size_t)(14 << 20));
    _Float16* Kb  = (_Float16*)(w + (size_t)(22 << 20));
    _Float16* Vt  = (_Float16*)(w + (size_t)(30 << 20));
    float* d2     = (float*)(w + (size_t)(38 << 20));

    k_convert_x<<<4096, 256, 0, stream>>>(x, xb);
    k_convert_wt<<<dim3(16, 16, 3), 256, 0, stream>>>(Wq, Wk, Wv, wbt);
    k_proj_gemm<<<dim3(24, 32), 256, 0, stream>>>(xb, wbt, bq, bk, bv, Qb, Kb, Vt);
    k_stats<<<1024, 256, 0, stream>>>(Qb, Kb, d2);
    k_attn<<<1024, 256, 0, stream>>>(Qb, Kb, Vt, d2, out);
}

// Round 12
// 216.093 us; speedup vs baseline: 1.0772x; 1.0663x over previous
//
#include <hip/hip_runtime.h>

// Problem: B=2, L=2048, E=1024, H=16, D=64
// softmax over QUERY axis (columns of the [L,M] score matrix per head).
//
// Softmax algebra: P[l,m] = 2^(S'[l,m] - d2_m), S' = log2(e)*S (folded into Q),
// d2_m = log2(sum_l 2^(S'[l,m])).  No max-subtraction (S ~ N(0,64)).
//
// Round-10 lesson: ~77us k_attn invariant across {LDS-roundtrip, bpermute} x
// {1,2 waves/SIMD} with all pipes <23% -> limiter is the 16-segment global
// gather per fragment load (L1-thrashing, L2 round trips through limited
// per-CU outstanding-request capacity).  Round-11: stage K/V/Q tiles in LDS
// via global_load_lds DMA (dense 1KB bursts), shared across the block's 4
// waves.  XOR swizzle (slot ^= row&7) applied on the GLOBAL SOURCE side +
// on the LDS read side (DMA dest must be linear) -> conflict-free
// ds_read_b128 fragments.  P relayout stays in-register (r10 bpermute,
// verified).  No m-split -> no final combine.
// (Round-11 run was an infra container failure; identical resubmission.)

typedef _Float16 f16x8 __attribute__((ext_vector_type(8)));
typedef _Float16 f16x4 __attribute__((ext_vector_type(4)));
typedef __fp16 fp16x2 __attribute__((ext_vector_type(2)));  // cvt_pkrtz ret type
typedef float f32x4 __attribute__((ext_vector_type(4)));

#define MFMA(a, b, c) __builtin_amdgcn_mfma_f32_16x16x32_f16((a), (b), (c), 0, 0, 0)
#define EXP2(x) __builtin_amdgcn_exp2f(x)
#define LOG2E 1.44269504088896340736f

// global -> LDS direct DMA, 16B per lane; dest = lds base + lane*16 (linear!)
#define GLOAD_LDS(gp, lp)                                                    \
    __builtin_amdgcn_global_load_lds(                                        \
        (const __attribute__((address_space(1))) void*)(const void*)(gp),    \
        (__attribute__((address_space(3))) void*)(void*)(lp), 16, 0, 0)

// ---------------------------------------------------------------------------
// Kernel 1: fp32 -> f16 convert of x  (4096x1024)
// ---------------------------------------------------------------------------
__global__ __launch_bounds__(256) void k_convert_x(const float* __restrict__ x,
                                                   _Float16* __restrict__ xb) {
    int i = (blockIdx.x * 256 + threadIdx.x) * 4;
    float4 f = *(const float4*)(x + i);
    f16x4 o = {(_Float16)f.x, (_Float16)f.y, (_Float16)f.z, (_Float16)f.w};
    *(f16x4*)(xb + i) = o;
}

// ---------------------------------------------------------------------------
// Kernel 2: W (k-major [E][E]) -> W^T f16 ([3*E rows = n][E cols = k])
// ---------------------------------------------------------------------------
__global__ __launch_bounds__(256) void k_convert_wt(const float* __restrict__ Wq,
                                                    const float* __restrict__ Wk,
                                                    const float* __restrict__ Wv,
                                                    _Float16* __restrict__ wbt) {
    const int jz = blockIdx.z;
    const float* W = (jz == 0) ? Wq : (jz == 1) ? Wk : Wv;
    __shared__ float tile[64][65];
    const int k0 = blockIdx.y * 64, n0 = blockIdx.x * 64;
    for (int e = threadIdx.x; e < 4096; e += 256) {
        int r = e >> 6, c = e & 63;
        tile[r][c] = W[(k0 + r) * 1024 + n0 + c];
    }
    __syncthreads();
    for (int e = threadIdx.x; e < 4096; e += 256) {
        int r = e >> 6, c = e & 63;
        wbt[((size_t)jz * 1024 + n0 + r) * 1024 + k0 + c] = (_Float16)tile[c][r];
    }
}

// ---------------------------------------------------------------------------
// Kernel 3: fused QKV projection GEMM (Q scaled by log2e for exp2 downstream).
// m97 structure: 128x128 tile, BK=32, global_load_lds staging (round-7 win).
// ---------------------------------------------------------------------------
__global__ __launch_bounds__(256) void k_proj_gemm(const _Float16* __restrict__ xb,
                                                   const _Float16* __restrict__ wbt,
                                                   const float* __restrict__ bq,
                                                   const float* __restrict__ bk,
                                                   const float* __restrict__ bv,
                                                   _Float16* __restrict__ Qb,
                                                   _Float16* __restrict__ Kb,
                                                   _Float16* __restrict__ Vt) {
    const int n0 = blockIdx.x * 128;
    const int m0 = blockIdx.y * 128;
    __shared__ _Float16 As[128][32];  // LINEAR (no pad): global_load_lds dest
    __shared__ _Float16 Bs[128][32];
    const int tid = threadIdx.x;
    const int lane = tid & 63, wv = tid >> 6;
    const int l15 = lane & 15, quad = lane >> 4;
    const int wr = wv >> 1, wc = wv & 1;
    const int srow = lane >> 2, scol = (lane & 3) * 8;

    f32x4 acc[4][4] = {};
    for (int k0 = 0; k0 < 1024; k0 += 32) {
        __syncthreads();
        #pragma unroll
        for (int j = 0; j < 2; ++j) {
            const int grp = j * 4 + wv;  // 0..7: 8 groups of 16 rows
            GLOAD_LDS(&xb[(size_t)(m0 + grp * 16 + srow) * 1024 + k0 + scol],
                      &As[grp * 16][0]);
            GLOAD_LDS(&wbt[(size_t)(n0 + grp * 16 + srow) * 1024 + k0 + scol],
                      &Bs[grp * 16][0]);
        }
        __syncthreads();
        f16x8 af[4], bf[4];
        #pragma unroll
        for (int i = 0; i < 4; ++i) {
            af[i] = *(const f16x8*)&As[wr * 64 + i * 16 + l15][quad * 8];
            bf[i] = *(const f16x8*)&Bs[wc * 64 + i * 16 + l15][quad * 8];
        }
        #pragma unroll
        for (int i = 0; i < 4; ++i)
            #pragma unroll
            for (int j = 0; j < 4; ++j)
                acc[i][j] = MFMA(af[i], bf[j], acc[i][j]);
    }

    const int proj = n0 >> 10;
    const float* bias = (proj == 0) ? bq : (proj == 1) ? bk : bv;
    const float scale = (proj == 0) ? LOG2E : 1.0f;
    for (int j = 0; j < 4; ++j) {
        int n = n0 + wc * 64 + j * 16 + l15;
        int nn = n & 1023;
        float bsv = bias[nn];
        int h = nn >> 6, d = nn & 63;
        for (int i = 0; i < 4; ++i) {
            for (int r = 0; r < 4; ++r) {
                int t = m0 + wr * 64 + i * 16 + quad * 4 + r;
                int b = t >> 11, l = t & 2047;
                _Float16 val = (_Float16)((acc[i][j][r] + bsv) * scale);
                int bh = b * 16 + h;
                if (proj == 0)
                    Qb[((size_t)bh * 2048 + l) * 64 + d] = val;
                else if (proj == 1)
                    Kb[((size_t)bh * 2048 + l) * 64 + d] = val;
                else
                    Vt[((size_t)bh * 64 + d) * 2048 + l] = val;
            }
        }
    }
}

// ---------------------------------------------------------------------------
// Kernel 4: column stats d2_m = log2(sum_l 2^(S'[l,m])).
// Block = 64 m-cols of one head, 4 waves.  Q staged per 128-l chunk via
// global_load_lds (source-side XOR swizzle), shared by all 4 waves; wave w
// computes l-rows w*32..w*32+31 of each chunk.  K frags register-resident.
// Partial exp-sums combined exactly in LDS at the end.  1024 blocks.
// ---------------------------------------------------------------------------
__global__ __launch_bounds__(256, 2) void k_stats(const _Float16* __restrict__ Qb,
                                                  const _Float16* __restrict__ Kb,
                                                  float* __restrict__ d2) {
    __shared__ _Float16 Qs[128][64];            // 16 KB staged Q chunk
    __shared__ float sred[4][4][64];            // 4 KB combine
    const int id = blockIdx.x;                  // 1024 blocks
    const int wk = (id & 7) * 128 + (id >> 3);  // XCD swizzle
    const int bh = wk >> 5;                     // 32 heads
    const int mt = wk & 31;                     // 32 m-tiles of 64
    const int lane = threadIdx.x & 63, wv = threadIdx.x >> 6;
    const int l15 = lane & 15, quad = lane >> 4;
    const int m0 = mt * 64;
    const size_t base = (size_t)bh * 2048 * 64;
    const _Float16* Kp = Kb + base;
    const _Float16* Qp = Qb + base;
    const int sw = l15 & 7;                     // read-side XOR key

    // K fragments (X-operand rows = m): loop-invariant, one-time gather
    f16x8 bf[4][2];
    #pragma unroll
    for (int s = 0; s < 4; ++s) {
        bf[s][0] = *(const f16x8*)&Kp[(size_t)(m0 + s * 16 + l15) * 64 + quad * 8];
        bf[s][1] = *(const f16x8*)&Kp[(size_t)(m0 + s * 16 + l15) * 64 + 32 + quad * 8];
    }
    // staging offsets: wave w stages groups 4w..4w+3 (8 rows x 128B each);
    // src slot pre-swizzled so linear DMA dest + XOR read = swizzled layout.
    int qoff[4];
    #pragma unroll
    for (int j = 0; j < 4; ++j) {
        int r = (4 * wv + j) * 8 + (lane >> 3);
        int ss = (lane & 7) ^ (r & 7);
        qoff[j] = r * 64 + ss * 8;
    }
    float rs[4] = {0.f, 0.f, 0.f, 0.f};

    for (int ch = 0; ch < 16; ++ch) {
        const _Float16* qc = Qp + (size_t)ch * 8192;  // 128 rows x 64
        #pragma unroll
        for (int j = 0; j < 4; ++j)
            GLOAD_LDS(qc + qoff[j], &Qs[(4 * wv + j) * 8][0]);
        __syncthreads();  // DMA drained + all waves staged
        __builtin_amdgcn_s_setprio(1);
        #pragma unroll
        for (int lt = 0; lt < 2; ++lt) {
            const int row = wv * 32 + lt * 16 + l15;
            f16x8 q0 = *(const f16x8*)&Qs[row][((0 + quad) ^ sw) * 8];
            f16x8 q1 = *(const f16x8*)&Qs[row][((4 + quad) ^ sw) * 8];
            #pragma unroll
            for (int s = 0; s < 4; ++s) {
                f32x4 a = {};
                a = MFMA(q0, bf[s][0], a);
                a = MFMA(q1, bf[s][1], a);
                rs[s] += EXP2(a[0]) + EXP2(a[1]) + EXP2(a[2]) + EXP2(a[3]);
            }
        }
        __builtin_amdgcn_s_setprio(0);
        __syncthreads();  // compute done before next chunk overwrites Qs
    }

    // combine wave partials (exact: plain sum; waves cover disjoint l)
    #pragma unroll
    for (int s = 0; s < 4; ++s) sred[wv][s][lane] = rs[s];
    __syncthreads();
    if (wv == 0) {
        #pragma unroll
        for (int s = 0; s < 4; ++s) {
            float t = sred[0][s][lane] + sred[1][s][lane] + sred[2][s][lane] + sred[3][s][lane];
            t += __shfl_xor(t, 16, 64);
            t += __shfl_xor(t, 32, 64);
            rs[s] = t;
        }
        float myz = (quad == 0) ? rs[0] : (quad == 1) ? rs[1] : (quad == 2) ? rs[2] : rs[3];
        d2[bh * 2048 + m0 + quad * 16 + l15] = __builtin_amdgcn_logf(myz);  // v_log = log2
    }
}

// ---------------------------------------------------------------------------
// Kernel 5: output.  Block = 128 l-rows of one head (4 waves x 32 l); loops
// m in staged 64-tiles: K-tile [64m][64d] 8KB + V-tile [64d][64m] 8KB DMA'd
// per chunk (4 issues/wave, source-side XOR swizzle), d2 staged once (8KB).
// Fragments via conflict-free ds_read_b128.  Swapped QK -> in-register
// bpermute P relayout (r10-verified) -> swapped PV.  Each wave owns full m
// for its 32 l -> NO final combine.  512 blocks (2/CU, 8 waves/CU).
// ---------------------------------------------------------------------------
__global__ __launch_bounds__(256, 2) void k_attn(const _Float16* __restrict__ Qb,
                                                 const _Float16* __restrict__ Kb,
                                                 const _Float16* __restrict__ Vt,
                                                 const float* __restrict__ d2,
                                                 float* __restrict__ out) {
    __shared__ _Float16 Ks[64][64];             // 8 KB K tile [m][d]
    __shared__ _Float16 Vs[64][64];             // 8 KB V tile [d][m]
    __shared__ float d2s[2048];                 // 8 KB (staged once)
    const int id = blockIdx.x;                  // 512 blocks
    const int wk = (id & 7) * 64 + (id >> 3);   // XCD swizzle (512 = 8*64)
    const int bh = wk >> 4;                     // 32 heads
    const int ltile = wk & 15;                  // 16 l-tiles of 128
    const int b = bh >> 4, h = bh & 15;
    const int lane = threadIdx.x & 63, wv = threadIdx.x >> 6;
    const int l15 = lane & 15, quad = lane >> 4;
    const int lw = ltile * 128 + wv * 32;       // wave's 32 l-rows
    const size_t base = (size_t)bh * 2048 * 64;
    const _Float16* Qp = Qb + base;
    const _Float16* Kp = Kb + base;
    const _Float16* Vp = Vt + base;
    const float* d2p = d2 + bh * 2048;
    const int sw = l15 & 7;                     // read-side XOR key
    // bpermute byte-indices (r10-verified pull mapping)
    const int srcA = (l15 + ((quad & 1) << 5)) << 2;
    const int srcB = srcA + 64;
    const bool slo = (quad < 2);

    // stage d2 once: 8 groups of 256 floats; wave w: groups 2w, 2w+1
    GLOAD_LDS(d2p + (2 * wv) * 256 + lane * 4, &d2s[(2 * wv) * 256]);
    GLOAD_LDS(d2p + (2 * wv + 1) * 256 + lane * 4, &d2s[(2 * wv + 1) * 256]);

    // Q fragments: one-time global gather, loop-invariant
    f16x8 qf[2][2];
    #pragma unroll
    for (int lt = 0; lt < 2; ++lt) {
        qf[lt][0] = *(const f16x8*)&Qp[(size_t)(lw + lt * 16 + l15) * 64 + quad * 8];
        qf[lt][1] = *(const f16x8*)&Qp[(size_t)(lw + lt * 16 + l15) * 64 + 32 + quad * 8];
    }
    f32x4 oacc[4][2] = {};  // [dt][lt]: lane holds out[d=dt*16+quad*4+r][l=lt*16+l15]

    // staging offsets: wave w stages rows 16w..16w+15 of each tile (2 groups)
    const int r0 = 16 * wv + (lane >> 3), r1 = r0 + 8;
    const int ss0 = (lane & 7) ^ (r0 & 7), ss1 = (lane & 7) ^ (r1 & 7);
    const size_t ko0 = (size_t)r0 * 64 + ss0 * 8, ko1 = (size_t)r1 * 64 + ss1 * 8;
    const size_t vo0 = (size_t)r0 * 2048 + ss0 * 8, vo1 = (size_t)r1 * 2048 + ss1 * 8;

    for (int ch = 0; ch < 32; ++ch) {
        const _Float16* kc = Kp + (size_t)ch * 4096;  // 64 m-rows x 64
        const _Float16* vc = Vp + ch * 64;            // 64 m-cols within d-rows
        GLOAD_LDS(kc + ko0, &Ks[16 * wv][0]);
        GLOAD_LDS(kc + ko1, &Ks[16 * wv + 8][0]);
        GLOAD_LDS(vc + vo0, &Vs[16 * wv][0]);
        GLOAD_LDS(vc + vo1, &Vs[16 * wv + 8][0]);
        __syncthreads();  // DMA drained (incl. first-iter d2s) + staged
        __builtin_amdgcn_s_setprio(1);
        #pragma unroll
        for (int sub = 0; sub < 2; ++sub) {
            f32x4 dvv[2];
            #pragma unroll
            for (int s = 0; s < 2; ++s)
                dvv[s] = *(const f32x4*)&d2s[ch * 64 + sub * 32 + s * 16 + quad * 4];
            f16x8 kf[2][2];
            #pragma unroll
            for (int s = 0; s < 2; ++s) {
                const int row = sub * 32 + s * 16 + l15;
                kf[s][0] = *(const f16x8*)&Ks[row][((0 + quad) ^ sw) * 8];
                kf[s][1] = *(const f16x8*)&Ks[row][((4 + quad) ^ sw) * 8];
            }
            f16x8 vfr[4];
            #pragma unroll
            for (int dt = 0; dt < 4; ++dt)
                vfr[dt] = *(const f16x8*)&Vs[dt * 16 + l15][((sub * 4 + quad) ^ sw) * 8];
            #pragma unroll
            for (int lt = 0; lt < 2; ++lt) {
                unsigned int c[2][2];
                #pragma unroll
                for (int s = 0; s < 2; ++s) {
                    f32x4 a = {};
                    a = MFMA(kf[s][0], qf[lt][0], a);
                    a = MFMA(kf[s][1], qf[lt][1], a);
                    union { fp16x2 hh; unsigned int u; } u0, u1;
                    u0.hh = __builtin_amdgcn_cvt_pkrtz(EXP2(a[0] - dvv[s][0]),
                                                       EXP2(a[1] - dvv[s][1]));
                    u1.hh = __builtin_amdgcn_cvt_pkrtz(EXP2(a[2] - dvv[s][2]),
                                                       EXP2(a[3] - dvv[s][3]));
                    c[s][0] = u0.u;
                    c[s][1] = u1.u;
                }
                int t0a = __builtin_amdgcn_ds_bpermute(srcA, (int)c[0][0]);
                int t1a = __builtin_amdgcn_ds_bpermute(srcA, (int)c[1][0]);
                int t0b = __builtin_amdgcn_ds_bpermute(srcA, (int)c[0][1]);
                int t1b = __builtin_amdgcn_ds_bpermute(srcA, (int)c[1][1]);
                int t0c = __builtin_amdgcn_ds_bpermute(srcB, (int)c[0][0]);
                int t1c = __builtin_amdgcn_ds_bpermute(srcB, (int)c[1][0]);
                int t0d = __builtin_amdgcn_ds_bpermute(srcB, (int)c[0][1]);
                int t1d = __builtin_amdgcn_ds_bpermute(srcB, (int)c[1][1]);
                union { int w[4]; f16x8 v; } pu;
                pu.w[0] = slo ? t0a : t1a;
                pu.w[1] = slo ? t0b : t1b;
                pu.w[2] = slo ? t0c : t1c;
                pu.w[3] = slo ? t0d : t1d;
                #pragma unroll
                for (int dt = 0; dt < 4; ++dt)
                    oacc[dt][lt] = MFMA(vfr[dt], pu.v, oacc[dt][lt]);
            }
        }
        __builtin_amdgcn_s_setprio(0);
        __syncthreads();  // compute done before next chunk overwrites Ks/Vs
    }

    // epilogue: direct store (no combine -- wave owns full m for its rows)
    #pragma unroll
    for (int lt = 0; lt < 2; ++lt)
        #pragma unroll
        for (int dt = 0; dt < 4; ++dt) {
            int l = lw + lt * 16 + l15;
            float4 o4 = {oacc[dt][lt][0], oacc[dt][lt][1], oacc[dt][lt][2], oacc[dt][lt][3]};
            *(float4*)&out[((size_t)(b * 2048 + l)) * 1024 + h * 64 + dt * 16 + quad * 4] = o4;
        }
}

// ---------------------------------------------------------------------------
// Workspace layout (bytes):
//  0        xb   : 4096*1024 f16          = 8 MB
//  8 MB     wbt  : 3072*1024 f16          = 6 MB
// 14 MB     Qb   : 32*2048*64 f16         = 8 MB   (pre-scaled by log2e)
// 22 MB     Kb   : 32*2048*64 f16         = 8 MB
// 30 MB     Vt   : 32*64*2048 f16         = 8 MB
// 38 MB     d2   : 32*2048 f32            = 256 KB (log2 of column expsum)
// ---------------------------------------------------------------------------
extern "C" void kernel_launch(void* const* d_in, const int* in_sizes, int n_in,
                              void* d_out, int out_size, void* d_ws, size_t ws_size,
                              hipStream_t stream) {
    const float* x  = (const float*)d_in[0];
    const float* Wq = (const float*)d_in[1];
    const float* bq = (const float*)d_in[2];
    const float* Wk = (const float*)d_in[3];
    const float* bk = (const float*)d_in[4];
    const float* Wv = (const float*)d_in[5];
    const float* bv = (const float*)d_in[6];
    float* out = (float*)d_out;

    char* w = (char*)d_ws;
    _Float16* xb  = (_Float16*)(w);
    _Float16* wbt = (_Float16*)(w + (size_t)(8 << 20));
    _Float16* Qb  = (_Float16*)(w + (size_t)(14 << 20));
    _Float16* Kb  = (_Float16*)(w + (size_t)(22 << 20));
    _Float16* Vt  = (_Float16*)(w + (size_t)(30 << 20));
    float* d2     = (float*)(w + (size_t)(38 << 20));

    k_convert_x<<<4096, 256, 0, stream>>>(x, xb);
    k_convert_wt<<<dim3(16, 16, 3), 256, 0, stream>>>(Wq, Wk, Wv, wbt);
    k_proj_gemm<<<dim3(24, 32), 256, 0, stream>>>(xb, wbt, bq, bk, bv, Qb, Kb, Vt);
    k_stats<<<1024, 256, 0, stream>>>(Qb, Kb, d2);
    k_attn<<<512, 256, 0, stream>>>(Qb, Kb, Vt, d2, out);
}

// Round 13
// 210.627 us; speedup vs baseline: 1.1051x; 1.0260x over previous
//
#include <hip/hip_runtime.h>

// Problem: B=2, L=2048, E=1024, H=16, D=64
// softmax over QUERY axis (columns of the [L,M] score matrix per head).
//
// Softmax algebra: P[l,m] = 2^(S'[l,m] - d2_m), S' = log2(e)*S (folded into Q),
// d2_m = log2(sum_l 2^(S'[l,m])).  No max-subtraction (S ~ N(0,64)).
//
// Round-12 lessons: (1) SQ_LDS_BANK_CONFLICT == 2^22 exactly in r10 AND r12
// -> it's the fixed 2-cycle ds_bpermute cost (2M/dispatch), not layout
// conflicts.  (2) stage->drain->compute serializes ~300-500cy of DMA latency
// into EVERY chunk (5400cy/chunk for ~2000cy compute).  Round-13: T3
// minimum-2-phase -- double-buffer Ks/Vs (and Qs in k_stats); issue next
// chunk's DMA FIRST, compute current buffer, ONE barrier per chunk.  The
// DMA gets the whole compute phase to land; loop unrolled x2 so the buffer
// index is compile-time.

typedef _Float16 f16x8 __attribute__((ext_vector_type(8)));
typedef _Float16 f16x4 __attribute__((ext_vector_type(4)));
typedef __fp16 fp16x2 __attribute__((ext_vector_type(2)));  // cvt_pkrtz ret type
typedef float f32x4 __attribute__((ext_vector_type(4)));

#define MFMA(a, b, c) __builtin_amdgcn_mfma_f32_16x16x32_f16((a), (b), (c), 0, 0, 0)
#define EXP2(x) __builtin_amdgcn_exp2f(x)
#define LOG2E 1.44269504088896340736f

// global -> LDS direct DMA, 16B per lane; dest = lds base + lane*16 (linear!)
#define GLOAD_LDS(gp, lp)                                                    \
    __builtin_amdgcn_global_load_lds(                                        \
        (const __attribute__((address_space(1))) void*)(const void*)(gp),    \
        (__attribute__((address_space(3))) void*)(void*)(lp), 16, 0, 0)

// ---------------------------------------------------------------------------
// Kernel 1: fp32 -> f16 convert of x  (4096x1024)
// ---------------------------------------------------------------------------
__global__ __launch_bounds__(256) void k_convert_x(const float* __restrict__ x,
                                                   _Float16* __restrict__ xb) {
    int i = (blockIdx.x * 256 + threadIdx.x) * 4;
    float4 f = *(const float4*)(x + i);
    f16x4 o = {(_Float16)f.x, (_Float16)f.y, (_Float16)f.z, (_Float16)f.w};
    *(f16x4*)(xb + i) = o;
}

// ---------------------------------------------------------------------------
// Kernel 2: W (k-major [E][E]) -> W^T f16 ([3*E rows = n][E cols = k])
// ---------------------------------------------------------------------------
__global__ __launch_bounds__(256) void k_convert_wt(const float* __restrict__ Wq,
                                                    const float* __restrict__ Wk,
                                                    const float* __restrict__ Wv,
                                                    _Float16* __restrict__ wbt) {
    const int jz = blockIdx.z;
    const float* W = (jz == 0) ? Wq : (jz == 1) ? Wk : Wv;
    __shared__ float tile[64][65];
    const int k0 = blockIdx.y * 64, n0 = blockIdx.x * 64;
    for (int e = threadIdx.x; e < 4096; e += 256) {
        int r = e >> 6, c = e & 63;
        tile[r][c] = W[(k0 + r) * 1024 + n0 + c];
    }
    __syncthreads();
    for (int e = threadIdx.x; e < 4096; e += 256) {
        int r = e >> 6, c = e & 63;
        wbt[((size_t)jz * 1024 + n0 + r) * 1024 + k0 + c] = (_Float16)tile[c][r];
    }
}

// ---------------------------------------------------------------------------
// Kernel 3: fused QKV projection GEMM (Q scaled by log2e for exp2 downstream).
// m97 structure: 128x128 tile, BK=32, global_load_lds staging (round-7 win).
// ---------------------------------------------------------------------------
__global__ __launch_bounds__(256) void k_proj_gemm(const _Float16* __restrict__ xb,
                                                   const _Float16* __restrict__ wbt,
                                                   const float* __restrict__ bq,
                                                   const float* __restrict__ bk,
                                                   const float* __restrict__ bv,
                                                   _Float16* __restrict__ Qb,
                                                   _Float16* __restrict__ Kb,
                                                   _Float16* __restrict__ Vt) {
    const int n0 = blockIdx.x * 128;
    const int m0 = blockIdx.y * 128;
    __shared__ _Float16 As[128][32];  // LINEAR (no pad): global_load_lds dest
    __shared__ _Float16 Bs[128][32];
    const int tid = threadIdx.x;
    const int lane = tid & 63, wv = tid >> 6;
    const int l15 = lane & 15, quad = lane >> 4;
    const int wr = wv >> 1, wc = wv & 1;
    const int srow = lane >> 2, scol = (lane & 3) * 8;

    f32x4 acc[4][4] = {};
    for (int k0 = 0; k0 < 1024; k0 += 32) {
        __syncthreads();
        #pragma unroll
        for (int j = 0; j < 2; ++j) {
            const int grp = j * 4 + wv;  // 0..7: 8 groups of 16 rows
            GLOAD_LDS(&xb[(size_t)(m0 + grp * 16 + srow) * 1024 + k0 + scol],
                      &As[grp * 16][0]);
            GLOAD_LDS(&wbt[(size_t)(n0 + grp * 16 + srow) * 1024 + k0 + scol],
                      &Bs[grp * 16][0]);
        }
        __syncthreads();
        f16x8 af[4], bf[4];
        #pragma unroll
        for (int i = 0; i < 4; ++i) {
            af[i] = *(const f16x8*)&As[wr * 64 + i * 16 + l15][quad * 8];
            bf[i] = *(const f16x8*)&Bs[wc * 64 + i * 16 + l15][quad * 8];
        }
        #pragma unroll
        for (int i = 0; i < 4; ++i)
            #pragma unroll
            for (int j = 0; j < 4; ++j)
                acc[i][j] = MFMA(af[i], bf[j], acc[i][j]);
    }

    const int proj = n0 >> 10;
    const float* bias = (proj == 0) ? bq : (proj == 1) ? bk : bv;
    const float scale = (proj == 0) ? LOG2E : 1.0f;
    for (int j = 0; j < 4; ++j) {
        int n = n0 + wc * 64 + j * 16 + l15;
        int nn = n & 1023;
        float bsv = bias[nn];
        int h = nn >> 6, d = nn & 63;
        for (int i = 0; i < 4; ++i) {
            for (int r = 0; r < 4; ++r) {
                int t = m0 + wr * 64 + i * 16 + quad * 4 + r;
                int b = t >> 11, l = t & 2047;
                _Float16 val = (_Float16)((acc[i][j][r] + bsv) * scale);
                int bh = b * 16 + h;
                if (proj == 0)
                    Qb[((size_t)bh * 2048 + l) * 64 + d] = val;
                else if (proj == 1)
                    Kb[((size_t)bh * 2048 + l) * 64 + d] = val;
                else
                    Vt[((size_t)bh * 64 + d) * 2048 + l] = val;
            }
        }
    }
}

// ---------------------------------------------------------------------------
// Kernel 4: column stats d2_m = log2(sum_l 2^(S'[l,m])).
// Block = 64 m-cols of one head, 4 waves.  Q double-buffer-staged per 128-l
// chunk via global_load_lds (source-side XOR swizzle): issue next chunk's
// DMA, compute current, one barrier.  K frags register-resident.  Partial
// exp-sums combined exactly in LDS at the end.  1024 blocks.
// ---------------------------------------------------------------------------
__global__ __launch_bounds__(256, 2) void k_stats(const _Float16* __restrict__ Qb,
                                                  const _Float16* __restrict__ Kb,
                                                  float* __restrict__ d2) {
    __shared__ _Float16 Qs[2][128][64];         // 32 KB double-buffered Q
    __shared__ float sred[4][4][64];            // 4 KB combine
    const int id = blockIdx.x;                  // 1024 blocks
    const int wk = (id & 7) * 128 + (id >> 3);  // XCD swizzle
    const int bh = wk >> 5;                     // 32 heads
    const int mt = wk & 31;                     // 32 m-tiles of 64
    const int lane = threadIdx.x & 63, wv = threadIdx.x >> 6;
    const int l15 = lane & 15, quad = lane >> 4;
    const int m0 = mt * 64;
    const size_t base = (size_t)bh * 2048 * 64;
    const _Float16* Kp = Kb + base;
    const _Float16* Qp = Qb + base;
    const int sw = l15 & 7;                     // read-side XOR key

    // K fragments (X-operand rows = m): loop-invariant, one-time gather
    f16x8 bf[4][2];
    #pragma unroll
    for (int s = 0; s < 4; ++s) {
        bf[s][0] = *(const f16x8*)&Kp[(size_t)(m0 + s * 16 + l15) * 64 + quad * 8];
        bf[s][1] = *(const f16x8*)&Kp[(size_t)(m0 + s * 16 + l15) * 64 + 32 + quad * 8];
    }
    // staging offsets: wave w stages groups 4w..4w+3 (8 rows x 128B each);
    // src slot pre-swizzled so linear DMA dest + XOR read = swizzled layout.
    int qoff[4];
    #pragma unroll
    for (int j = 0; j < 4; ++j) {
        int r = (4 * wv + j) * 8 + (lane >> 3);
        int ss = (lane & 7) ^ (r & 7);
        qoff[j] = r * 64 + ss * 8;
    }
    float rs[4] = {0.f, 0.f, 0.f, 0.f};

#define SSTAGE(P, CH) do {                                                   \
        const _Float16* qc_ = Qp + (size_t)(CH) * 8192;                      \
        _Pragma("unroll")                                                    \
        for (int j = 0; j < 4; ++j)                                          \
            GLOAD_LDS(qc_ + qoff[j], &Qs[P][(4 * wv + j) * 8][0]);           \
    } while (0)

#define SCOMP(P) do {                                                        \
        __builtin_amdgcn_s_setprio(1);                                       \
        _Pragma("unroll")                                                    \
        for (int lt = 0; lt < 2; ++lt) {                                     \
            const int row = wv * 32 + lt * 16 + l15;                         \
            f16x8 q0 = *(const f16x8*)&Qs[P][row][((0 + quad) ^ sw) * 8];    \
            f16x8 q1 = *(const f16x8*)&Qs[P][row][((4 + quad) ^ sw) * 8];    \
            _Pragma("unroll")                                                \
            for (int s = 0; s < 4; ++s) {                                    \
                f32x4 a = {};                                                \
                a = MFMA(q0, bf[s][0], a);                                   \
                a = MFMA(q1, bf[s][1], a);                                   \
                rs[s] += EXP2(a[0]) + EXP2(a[1]) + EXP2(a[2]) + EXP2(a[3]);  \
            }                                                                \
        }                                                                    \
        __builtin_amdgcn_s_setprio(0);                                       \
    } while (0)

    SSTAGE(0, 0);
    __syncthreads();  // prologue DMA drained
    for (int ch = 0; ch < 16; ch += 2) {
        SSTAGE(1, ch + 1);      // issue next (lands during compute)
        SCOMP(0);
        __syncthreads();        // buf0 reads done + buf1 DMA drained
        if (ch + 2 < 16) SSTAGE(0, ch + 2);
        SCOMP(1);
        __syncthreads();
    }
#undef SSTAGE
#undef SCOMP

    // combine wave partials (exact: plain sum; waves cover disjoint l)
    #pragma unroll
    for (int s = 0; s < 4; ++s) sred[wv][s][lane] = rs[s];
    __syncthreads();
    if (wv == 0) {
        #pragma unroll
        for (int s = 0; s < 4; ++s) {
            float t = sred[0][s][lane] + sred[1][s][lane] + sred[2][s][lane] + sred[3][s][lane];
            t += __shfl_xor(t, 16, 64);
            t += __shfl_xor(t, 32, 64);
            rs[s] = t;
        }
        float myz = (quad == 0) ? rs[0] : (quad == 1) ? rs[1] : (quad == 2) ? rs[2] : rs[3];
        d2[bh * 2048 + m0 + quad * 16 + l15] = __builtin_amdgcn_logf(myz);  // v_log = log2
    }
}

// ---------------------------------------------------------------------------
// Kernel 5: output.  Block = 128 l-rows of one head (4 waves x 32 l); m in
// DOUBLE-BUFFERED staged 64-tiles (K 8KB + V 8KB per buffer; issue next
// chunk's DMA, compute current, one barrier/chunk -- T3 2-phase).  d2 staged
// once.  Source-side XOR swizzle -> conflict-free ds_read_b128.  Swapped QK
// -> in-register bpermute P relayout (r10-verified) -> swapped PV.  No
// combine.  512 blocks, LDS 40KB.
// ---------------------------------------------------------------------------
__global__ __launch_bounds__(256, 2) void k_attn(const _Float16* __restrict__ Qb,
                                                 const _Float16* __restrict__ Kb,
                                                 const _Float16* __restrict__ Vt,
                                                 const float* __restrict__ d2,
                                                 float* __restrict__ out) {
    __shared__ _Float16 Ks[2][64][64];          // 16 KB K tiles [m][d]
    __shared__ _Float16 Vs[2][64][64];          // 16 KB V tiles [d][m]
    __shared__ float d2s[2048];                 // 8 KB (staged once)
    const int id = blockIdx.x;                  // 512 blocks
    const int wk = (id & 7) * 64 + (id >> 3);   // XCD swizzle (512 = 8*64)
    const int bh = wk >> 4;                     // 32 heads
    const int ltile = wk & 15;                  // 16 l-tiles of 128
    const int b = bh >> 4, h = bh & 15;
    const int lane = threadIdx.x & 63, wv = threadIdx.x >> 6;
    const int l15 = lane & 15, quad = lane >> 4;
    const int lw = ltile * 128 + wv * 32;       // wave's 32 l-rows
    const size_t base = (size_t)bh * 2048 * 64;
    const _Float16* Qp = Qb + base;
    const _Float16* Kp = Kb + base;
    const _Float16* Vp = Vt + base;
    const float* d2p = d2 + bh * 2048;
    const int sw = l15 & 7;                     // read-side XOR key
    // bpermute byte-indices (r10-verified pull mapping)
    const int srcA = (l15 + ((quad & 1) << 5)) << 2;
    const int srcB = srcA + 64;
    const bool slo = (quad < 2);

    // stage d2 once: 8 groups of 256 floats; wave w: groups 2w, 2w+1
    GLOAD_LDS(d2p + (2 * wv) * 256 + lane * 4, &d2s[(2 * wv) * 256]);
    GLOAD_LDS(d2p + (2 * wv + 1) * 256 + lane * 4, &d2s[(2 * wv + 1) * 256]);

    // Q fragments: one-time global gather, loop-invariant
    f16x8 qf[2][2];
    #pragma unroll
    for (int lt = 0; lt < 2; ++lt) {
        qf[lt][0] = *(const f16x8*)&Qp[(size_t)(lw + lt * 16 + l15) * 64 + quad * 8];
        qf[lt][1] = *(const f16x8*)&Qp[(size_t)(lw + lt * 16 + l15) * 64 + 32 + quad * 8];
    }
    f32x4 oacc[4][2] = {};  // [dt][lt]: lane holds out[d=dt*16+quad*4+r][l=lt*16+l15]

    // staging offsets: wave w stages rows 16w..16w+15 of each tile (2 groups)
    const int r0 = 16 * wv + (lane >> 3), r1 = r0 + 8;
    const int ss0 = (lane & 7) ^ (r0 & 7), ss1 = (lane & 7) ^ (r1 & 7);
    const size_t ko0 = (size_t)r0 * 64 + ss0 * 8, ko1 = (size_t)r1 * 64 + ss1 * 8;
    const size_t vo0 = (size_t)r0 * 2048 + ss0 * 8, vo1 = (size_t)r1 * 2048 + ss1 * 8;

#define ASTAGE(P, CH) do {                                                   \
        const _Float16* kc_ = Kp + (size_t)(CH) * 4096;                      \
        const _Float16* vc_ = Vp + (CH) * 64;                                \
        GLOAD_LDS(kc_ + ko0, &Ks[P][16 * wv][0]);                            \
        GLOAD_LDS(kc_ + ko1, &Ks[P][16 * wv + 8][0]);                        \
        GLOAD_LDS(vc_ + vo0, &Vs[P][16 * wv][0]);                            \
        GLOAD_LDS(vc_ + vo1, &Vs[P][16 * wv + 8][0]);                        \
    } while (0)

#define ACOMP(P, CH) do {                                                     \
        __builtin_amdgcn_s_setprio(1);                                        \
        _Pragma("unroll")                                                     \
        for (int sub = 0; sub < 2; ++sub) {                                   \
            f32x4 dvv[2];                                                     \
            _Pragma("unroll")                                                 \
            for (int s = 0; s < 2; ++s)                                       \
                dvv[s] = *(const f32x4*)&d2s[(CH) * 64 + sub * 32 + s * 16 + quad * 4]; \
            f16x8 kf[2][2];                                                   \
            _Pragma("unroll")                                                 \
            for (int s = 0; s < 2; ++s) {                                     \
                const int row = sub * 32 + s * 16 + l15;                      \
                kf[s][0] = *(const f16x8*)&Ks[P][row][((0 + quad) ^ sw) * 8]; \
                kf[s][1] = *(const f16x8*)&Ks[P][row][((4 + quad) ^ sw) * 8]; \
            }                                                                 \
            f16x8 vfr[4];                                                     \
            _Pragma("unroll")                                                 \
            for (int dt = 0; dt < 4; ++dt)                                    \
                vfr[dt] = *(const f16x8*)&Vs[P][dt * 16 + l15][((sub * 4 + quad) ^ sw) * 8]; \
            _Pragma("unroll")                                                 \
            for (int lt = 0; lt < 2; ++lt) {                                  \
                unsigned int c[2][2];                                         \
                _Pragma("unroll")                                             \
                for (int s = 0; s < 2; ++s) {                                 \
                    f32x4 a = {};                                             \
                    a = MFMA(kf[s][0], qf[lt][0], a);                         \
                    a = MFMA(kf[s][1], qf[lt][1], a);                         \
                    union { fp16x2 hh; unsigned int u; } u0, u1;              \
                    u0.hh = __builtin_amdgcn_cvt_pkrtz(EXP2(a[0] - dvv[s][0]),\
                                                       EXP2(a[1] - dvv[s][1]));\
                    u1.hh = __builtin_amdgcn_cvt_pkrtz(EXP2(a[2] - dvv[s][2]),\
                                                       EXP2(a[3] - dvv[s][3]));\
                    c[s][0] = u0.u;                                           \
                    c[s][1] = u1.u;                                           \
                }                                                             \
                int t0a = __builtin_amdgcn_ds_bpermute(srcA, (int)c[0][0]);   \
                int t1a = __builtin_amdgcn_ds_bpermute(srcA, (int)c[1][0]);   \
                int t0b = __builtin_amdgcn_ds_bpermute(srcA, (int)c[0][1]);   \
                int t1b = __builtin_amdgcn_ds_bpermute(srcA, (int)c[1][1]);   \
                int t0c = __builtin_amdgcn_ds_bpermute(srcB, (int)c[0][0]);   \
                int t1c = __builtin_amdgcn_ds_bpermute(srcB, (int)c[1][0]);   \
                int t0d = __builtin_amdgcn_ds_bpermute(srcB, (int)c[0][1]);   \
                int t1d = __builtin_amdgcn_ds_bpermute(srcB, (int)c[1][1]);   \
                union { int w[4]; f16x8 v; } pu;                              \
                pu.w[0] = slo ? t0a : t1a;                                    \
                pu.w[1] = slo ? t0b : t1b;                                    \
                pu.w[2] = slo ? t0c : t1c;                                    \
                pu.w[3] = slo ? t0d : t1d;                                    \
                _Pragma("unroll")                                             \
                for (int dt = 0; dt < 4; ++dt)                                \
                    oacc[dt][lt] = MFMA(vfr[dt], pu.v, oacc[dt][lt]);         \
            }                                                                 \
        }                                                                     \
        __builtin_amdgcn_s_setprio(0);                                        \
    } while (0)

    ASTAGE(0, 0);
    __syncthreads();  // prologue DMA (incl. d2s) drained
    for (int ch = 0; ch < 32; ch += 2) {
        ASTAGE(1, ch + 1);      // issue next chunk (lands during compute)
        ACOMP(0, ch);
        __syncthreads();        // buf0 reads done + buf1 DMA drained
        if (ch + 2 < 32) ASTAGE(0, ch + 2);
        ACOMP(1, ch + 1);
        __syncthreads();
    }
#undef ASTAGE
#undef ACOMP

    // epilogue: direct store (no combine -- wave owns full m for its rows)
    #pragma unroll
    for (int lt = 0; lt < 2; ++lt)
        #pragma unroll
        for (int dt = 0; dt < 4; ++dt) {
            int l = lw + lt * 16 + l15;
            float4 o4 = {oacc[dt][lt][0], oacc[dt][lt][1], oacc[dt][lt][2], oacc[dt][lt][3]};
            *(float4*)&out[((size_t)(b * 2048 + l)) * 1024 + h * 64 + dt * 16 + quad * 4] = o4;
        }
}

// ---------------------------------------------------------------------------
// Workspace layout (bytes):
//  0        xb   : 4096*1024 f16          = 8 MB
//  8 MB     wbt  : 3072*1024 f16          = 6 MB
// 14 MB     Qb   : 32*2048*64 f16         = 8 MB   (pre-scaled by log2e)
// 22 MB     Kb   : 32*2048*64 f16         = 8 MB
// 30 MB     Vt   : 32*64*2048 f16         = 8 MB
// 38 MB     d2   : 32*2048 f32            = 256 KB (log2 of column expsum)
// ---------------------------------------------------------------------------
extern "C" void kernel_launch(void* const* d_in, const int* in_sizes, int n_in,
                              void* d_out, int out_size, void* d_ws, size_t ws_size,
                              hipStream_t stream) {
    const float* x  = (const float*)d_in[0];
    const float* Wq = (const float*)d_in[1];
    const float* bq = (const float*)d_in[2];
    const float* Wk = (const float*)d_in[3];
    const float* bk = (const float*)d_in[4];
    const float* Wv = (const float*)d_in[5];
    const float* bv = (const float*)d_in[6];
    float* out = (float*)d_out;

    char* w = (char*)d_ws;
    _Float16* xb  = (_Float16*)(w);
    _Float16* wbt = (_Float16*)(w + (size_t)(8 << 20));
    _Float16* Qb  = (_Float16*)(w + (size_t)(14 << 20));
    _Float16* Kb  = (_Float16*)(w + (size_t)(22 << 20));
    _Float16* Vt  = (_Float16*)(w + (size_t)(30 << 20));
    float* d2     = (float*)(w + (size_t)(38 << 20));

    k_convert_x<<<4096, 256, 0, stream>>>(x, xb);
    k_convert_wt<<<dim3(16, 16, 3), 256, 0, stream>>>(Wq, Wk, Wv, wbt);
    k_proj_gemm<<<dim3(24, 32), 256, 0, stream>>>(xb, wbt, bq, bk, bv, Qb, Kb, Vt);
    k_stats<<<1024, 256, 0, stream>>>(Qb, Kb, d2);
    k_attn<<<512, 256, 0, stream>>>(Qb, Kb, Vt, d2, out);
}